// Round 13
// baseline (524.632 us; speedup 1.0000x reference)
//
#include <hip/hip_runtime.h>
#include <stdint.h>

#define B_N 2
#define S_N 2048
#define D_N 4096
#define H_N 32
#define KVH_N 8
#define HD_N 128
#define NQT (S_N / 64)
// 1/sqrt(128) * log2(e)  (Q prescale; softmax runs in exp2 domain)
#define QS_LOG2E 0.12751743f

typedef __attribute__((ext_vector_type(8))) short bf16x8;
typedef __attribute__((ext_vector_type(4))) float f32x4;

__device__ __forceinline__ unsigned short f2bf(float f) {
    union { float f; unsigned u; } v; v.f = f;
    unsigned u = v.u;
    u += 0x7fffu + ((u >> 16) & 1u);   // RNE
    return (unsigned short)(u >> 16);
}
__device__ __forceinline__ float bf2f(unsigned short h) {
    union { unsigned u; float f; } v; v.u = ((unsigned)h) << 16;
    return v.f;
}
__device__ __forceinline__ unsigned cvt_pk_bf16(float lo, float hi) {
    unsigned r;
    asm("v_cvt_pk_bf16_f32 %0, %1, %2" : "=v"(r) : "v"(lo), "v"(hi));
    return r;
}

__device__ __forceinline__ void gl16(const unsigned short* g, unsigned short* l) {
    __builtin_amdgcn_global_load_lds(
        (const __attribute__((address_space(1))) void*)g,
        (__attribute__((address_space(3))) void*)l, 16, 0, 0);
}

// ---------------- f32 -> bf16 conversion ----------------
__global__ void __launch_bounds__(256) conv_f32_bf16(const float* __restrict__ in,
                                                     unsigned short* __restrict__ out) {
    int i = (blockIdx.x * 256 + threadIdx.x) * 4;
    float4 v = *(const float4*)(in + i);
    ushort4 o;
    o.x = f2bf(v.x); o.y = f2bf(v.y); o.z = f2bf(v.z); o.w = f2bf(v.w);
    *(ushort4*)(out + i) = o;
}

// Fused x|wq|wk|wv -> contiguous bf16 workspace (xb|wb|wkv).
__global__ void __launch_bounds__(256) conv_multi(const float* __restrict__ x,
                                                  const float* __restrict__ wq,
                                                  const float* __restrict__ wk,
                                                  const float* __restrict__ wv,
                                                  unsigned short* __restrict__ dst) {
    size_t i = ((size_t)blockIdx.x * 256 + threadIdx.x) * 4;
    const float* s;
    if (i < 16777216u)      s = x  + i;
    else if (i < 33554432u) s = wq + (i - 16777216u);
    else if (i < 37748736u) s = wk + (i - 33554432u);
    else                    s = wv + (i - 37748736u);
    float4 v = *(const float4*)s;
    ushort4 o;
    o.x = f2bf(v.x); o.y = f2bf(v.y); o.z = f2bf(v.z); o.w = f2bf(v.w);
    *(ushort4*)(dst + i) = o;
}

// ========== 256x256 8-phase NT GEMM, R9 schedule + per-phase sched_barrier pins ==========
// MODE: 0 = bf16 out, 1 = f32 out, 2 = bf16 out + fused RoPE(Q) * QS_LOG2E.
#define BAR() __builtin_amdgcn_s_barrier()
#define VMC4() asm volatile("s_waitcnt vmcnt(4)" ::: "memory")
#define VMC2() asm volatile("s_waitcnt vmcnt(2)" ::: "memory")
#define PIN() __builtin_amdgcn_sched_barrier(0)

template<int MODE>
__global__ void __launch_bounds__(512, 2)
gemm256(const unsigned short* __restrict__ A, const unsigned short* __restrict__ Bm,
        void* __restrict__ Cv, int M, int N, int K,
        const float* __restrict__ fc, const float* __restrict__ fs) {
    __shared__ unsigned short ldsA[2][16384];
    __shared__ unsigned short ldsB[2][16384];

    const int tid = threadIdx.x;
    const int lane = tid & 63;
    const int w = tid >> 6;
    const int li = lane & 15, lg = lane >> 4;
    const int wr = w >> 2, wc = w & 3;

    const int nwg = gridDim.x;
    const int cpx = nwg >> 3;
    const int wg = (blockIdx.x & 7) * cpx + (blockIdx.x >> 3);
    const int nbn = N >> 8;
    const int bm = wg / nbn, bn = wg - bm * nbn;
    const int m0 = bm << 8, n0 = bn << 8;

    const int rbase = ((tid >> 7) << 4) + ((tid >> 2) & 15);
    const int cstg = ((tid >> 6) & 1) * 32 + (((tid & 3) * 8) ^ (((tid >> 5) & 1) << 4));
    const unsigned short* Abase = A + (size_t)(m0 + rbase) * K + cstg;
    const unsigned short* Bbase = Bm + (size_t)(n0 + rbase) * K + cstg;
    const int dstoff = tid * 8;
    const int kmask = K - 1;

    f32x4 acc[8][4];
#pragma unroll
    for (int i = 0; i < 8; ++i)
#pragma unroll
        for (int j = 0; j < 4; ++j) acc[i][j] = (f32x4){0.f, 0.f, 0.f, 0.f};

    const int colpart = (lg * 16) ^ ((li >> 3) << 5);

#define STG(BASE, LDSBUF, H, T) do {                                              \
        int kk_ = ((T) * 64) & kmask;                                             \
        gl16(BASE + (size_t)(((H) * 2 + 0) * 64) * K + kk_,                       \
             &LDSBUF[((H) * 2 + 0) * 4096 + dstoff]);                             \
        gl16(BASE + (size_t)(((H) * 2 + 1) * 64) * K + kk_,                       \
             &LDSBUF[((H) * 2 + 1) * 4096 + dstoff]);                             \
    } while (0)

#define LDBs(set, buf) do {                                                       \
        _Pragma("unroll")                                                         \
        for (int ni_ = 0; ni_ < 4; ++ni_) {                                       \
            _Pragma("unroll")                                                     \
            for (int ks_ = 0; ks_ < 2; ++ks_)                                     \
                bfr[set][ni_][ks_] = *(const bf16x8*)((const char*)&ldsB[buf][0]  \
                    + (wc * 4 + ni_) * 2048 + ks_ * 1024 + li * 64 + colpart);    \
        }                                                                         \
    } while (0)

#define LDAs(set, buf, q) do {                                                    \
        _Pragma("unroll")                                                         \
        for (int m_ = 0; m_ < 2; ++m_) {                                          \
            _Pragma("unroll")                                                     \
            for (int ks_ = 0; ks_ < 2; ++ks_)                                     \
                af[set][m_][ks_] = *(const bf16x8*)((const char*)&ldsA[buf][0]    \
                    + (wr * 8 + (q) * 2 + m_) * 2048 + ks_ * 1024 + li * 64 + colpart); \
        }                                                                         \
    } while (0)

#define MFMAs(sb, sa, q) do {                                                     \
        __builtin_amdgcn_s_setprio(1);                                            \
        _Pragma("unroll")                                                         \
        for (int ks_ = 0; ks_ < 2; ++ks_) {                                       \
            _Pragma("unroll")                                                     \
            for (int m_ = 0; m_ < 2; ++m_) {                                      \
                _Pragma("unroll")                                                 \
                for (int ni_ = 0; ni_ < 4; ++ni_)                                 \
                    acc[(q) * 2 + m_][ni_] = __builtin_amdgcn_mfma_f32_16x16x32_bf16( \
                        af[sa][m_][ks_], bfr[sb][ni_][ks_], acc[(q) * 2 + m_][ni_], 0, 0, 0); \
            }                                                                     \
        }                                                                         \
        __builtin_amdgcn_s_setprio(0);                                            \
    } while (0)

    STG(Abase, ldsA[0], 0, 0); STG(Abase, ldsA[0], 1, 0);
    STG(Bbase, ldsB[0], 0, 0); STG(Bbase, ldsB[0], 1, 0);
    STG(Bbase, ldsB[1], 0, 1); STG(Bbase, ldsB[1], 1, 1);
    VMC4();
    BAR();

    bf16x8 bfr[2][4][2], af[2][2][2];
    LDBs(0, 0);
    LDAs(0, 0, 0);

    const int NIT = K >> 7;
#pragma unroll 1
    for (int i = 0; i < NIT; ++i) {
        const int T = 2 * i;
        // ph1
        LDAs(1, 0, 1);
        STG(Abase, ldsA[1], 0, T + 1);
        PIN();
        MFMAs(0, 0, 0);
        PIN();
        BAR();
        // ph2
        LDAs(0, 0, 2);
        STG(Abase, ldsA[1], 1, T + 1);
        STG(Bbase, ldsB[0], 0, T + 2);
        PIN();
        MFMAs(0, 1, 1);
        PIN();
        BAR();
        // ph3
        LDAs(1, 0, 3);
        STG(Bbase, ldsB[0], 1, T + 2);
        PIN();
        MFMAs(0, 0, 2);
        PIN();
        VMC4();
        BAR();
        // ph4
        LDBs(1, 1);
        LDAs(0, 1, 0);
        PIN();
        MFMAs(0, 1, 3);
        PIN();
        BAR();
        // ph5
        LDAs(1, 1, 1);
        STG(Abase, ldsA[0], 0, T + 2);
        PIN();
        MFMAs(1, 0, 0);
        PIN();
        BAR();
        // ph6
        LDAs(0, 1, 2);
        STG(Abase, ldsA[0], 1, T + 2);
        STG(Bbase, ldsB[1], 0, T + 3);
        PIN();
        MFMAs(1, 1, 1);
        PIN();
        BAR();
        // ph7
        LDAs(1, 1, 3);
        STG(Bbase, ldsB[1], 1, T + 3);
        PIN();
        MFMAs(1, 0, 2);
        PIN();
        VMC4();
        BAR();
        // ph8
        LDBs(0, 0);
        LDAs(0, 0, 0);
        PIN();
        MFMAs(1, 1, 3);
        PIN();
        BAR();
    }

    const int r0 = m0 + wr * 128 + lg * 4;
    const int c0 = n0 + wc * 64 + li;
    if (MODE == 1) {
        float* C = (float*)Cv;
#pragma unroll
        for (int mi = 0; mi < 8; ++mi)
#pragma unroll
            for (int ni = 0; ni < 4; ++ni)
#pragma unroll
                for (int rr = 0; rr < 4; ++rr)
                    C[(size_t)(r0 + mi * 16 + rr) * N + c0 + ni * 16] = acc[mi][ni][rr];
    } else if (MODE == 0) {
        unsigned short* C = (unsigned short*)Cv;
#pragma unroll
        for (int mi = 0; mi < 8; ++mi)
#pragma unroll
            for (int ni = 0; ni < 4; ++ni)
#pragma unroll
                for (int rr = 0; rr < 4; ++rr)
                    C[(size_t)(r0 + mi * 16 + rr) * N + c0 + ni * 16] = f2bf(acc[mi][ni][rr]);
    } else {
        // fused RoPE(Q) + QS_LOG2E prescale
        unsigned short* C = (unsigned short*)Cv;
        const float sgn = (li & 1) ? 1.f : -1.f;
#pragma unroll
        for (int mi = 0; mi < 8; ++mi)
#pragma unroll
            for (int rr = 0; rr < 4; ++rr) {
                const int row = r0 + mi * 16 + rr;
                const int sidx = (row & (S_N - 1)) * 64;
#pragma unroll
                for (int ni = 0; ni < 4; ++ni) {
                    const int col = c0 + ni * 16;
                    const int ii = sidx + ((col & 127) >> 1);
                    float v = acc[mi][ni][rr];
                    float p = __shfl_xor(v, 1);
                    float o = (v * fc[ii] + sgn * p * fs[ii]) * QS_LOG2E;
                    C[(size_t)row * N + col] = f2bf(o);
                }
            }
    }
#undef STG
#undef LDBs
#undef LDAs
#undef MFMAs
}

// ========================= 256x128 8-phase NT GEMM (R10-R12 proven + pins) =========
template<int ROPEK>
__global__ void __launch_bounds__(512, 2)
gemm256x128(const unsigned short* __restrict__ A, const unsigned short* __restrict__ Bm,
            void* __restrict__ Cv, int M, int N, int K,
            const float* __restrict__ fc, const float* __restrict__ fs) {
    __shared__ unsigned short ldsA[2][16384];
    __shared__ unsigned short ldsB[2][8192];

    const int tid = threadIdx.x;
    const int lane = tid & 63;
    const int w = tid >> 6;
    const int li = lane & 15, lg = lane >> 4;
    const int wr = w >> 1, wc = w & 1;

    const int nwg = gridDim.x;
    const int cpx = nwg >> 3;
    const int wg = (blockIdx.x & 7) * cpx + (blockIdx.x >> 3);
    const int nbn = N >> 7;
    const int bm = wg / nbn, bn = wg - bm * nbn;
    const int m0 = bm << 8, n0 = bn << 7;

    const int rbase = ((tid >> 7) << 4) + ((tid >> 2) & 15);
    const int cstg = ((tid >> 6) & 1) * 32 + (((tid & 3) * 8) ^ (((tid >> 5) & 1) << 4));
    const unsigned short* Asrc[4];
    const unsigned short* Bsrc[2];
#pragma unroll
    for (int hj = 0; hj < 4; ++hj)
        Asrc[hj] = A + (size_t)(m0 + hj * 64 + rbase) * K + cstg;
#pragma unroll
    for (int hj = 0; hj < 2; ++hj)
        Bsrc[hj] = Bm + (size_t)(n0 + hj * 64 + rbase) * K + cstg;
    const int dstoff = tid * 8;
    const int kmask = K - 1;

    f32x4 acc[4][4];
#pragma unroll
    for (int i = 0; i < 4; ++i)
#pragma unroll
        for (int j = 0; j < 4; ++j) acc[i][j] = (f32x4){0.f, 0.f, 0.f, 0.f};

    const int colpart = (lg * 16) ^ ((li >> 3) << 5);

#define STG2(SRC, LDSBUF, H, T) do {                                        \
        int kk_ = ((T) * 64) & kmask;                                       \
        gl16(SRC[(H)*2 + 0] + kk_, &LDSBUF[((H)*2 + 0) * 4096 + dstoff]);   \
        gl16(SRC[(H)*2 + 1] + kk_, &LDSBUF[((H)*2 + 1) * 4096 + dstoff]);   \
    } while (0)

#define LDB2(buf) do {                                                       \
        _Pragma("unroll")                                                    \
        for (int ni_ = 0; ni_ < 4; ++ni_) {                                  \
            _Pragma("unroll")                                                \
            for (int ks_ = 0; ks_ < 2; ++ks_)                                \
                bfr[ni_][ks_] = *(const bf16x8*)((const char*)&ldsB[buf][0]  \
                    + (wc * 4 + ni_) * 2048 + ks_ * 1024 + li * 64 + colpart); \
        }                                                                    \
    } while (0)

#define LDA2(buf, q) do {                                                    \
        _Pragma("unroll")                                                    \
        for (int ks_ = 0; ks_ < 2; ++ks_)                                    \
            af2[ks_] = *(const bf16x8*)((const char*)&ldsA[buf][0]           \
                + (wr * 4 + (q)) * 2048 + ks_ * 1024 + li * 64 + colpart);   \
    } while (0)

#define MFMA8(q) do {                                                        \
        __builtin_amdgcn_s_setprio(1);                                       \
        _Pragma("unroll")                                                    \
        for (int ks_ = 0; ks_ < 2; ++ks_) {                                  \
            _Pragma("unroll")                                                \
            for (int ni_ = 0; ni_ < 4; ++ni_)                                \
                acc[q][ni_] = __builtin_amdgcn_mfma_f32_16x16x32_bf16(       \
                    af2[ks_], bfr[ni_][ks_], acc[q][ni_], 0, 0, 0);          \
        }                                                                    \
        __builtin_amdgcn_s_setprio(0);                                       \
    } while (0)

    STG2(Asrc, ldsA[0], 0, 0); STG2(Asrc, ldsA[0], 1, 0);
    STG2(Bsrc, ldsB[0], 0, 0);
    STG2(Bsrc, ldsB[1], 0, 1);
    VMC2();
    BAR();

    const int NIT = K >> 7;
    bf16x8 bfr[4][2], af2[2];
#pragma unroll 1
    for (int i = 0; i < NIT; ++i) {
        const int T = 2 * i;
        LDB2(0); LDA2(0, 0);
        STG2(Asrc, ldsA[1], 0, T + 1);
        PIN();
        BAR(); MFMA8(0); BAR();
        LDA2(0, 1);
        STG2(Asrc, ldsA[1], 1, T + 1);
        PIN();
        BAR(); MFMA8(1); BAR();
        LDA2(0, 2);
        STG2(Bsrc, ldsB[0], 0, T + 2);
        PIN();
        BAR(); MFMA8(2); BAR();
        LDA2(0, 3);
        PIN();
        VMC2();
        BAR(); MFMA8(3); BAR();
        LDB2(1); LDA2(1, 0);
        STG2(Asrc, ldsA[0], 0, T + 2);
        PIN();
        BAR(); MFMA8(0); BAR();
        LDA2(1, 1);
        STG2(Asrc, ldsA[0], 1, T + 2);
        PIN();
        BAR(); MFMA8(1); BAR();
        LDA2(1, 2);
        STG2(Bsrc, ldsB[1], 0, T + 3);
        PIN();
        BAR(); MFMA8(2); BAR();
        LDA2(1, 3);
        PIN();
        VMC2();
        BAR(); MFMA8(3); BAR();
    }

    const int r0 = m0 + wr * 64 + lg * 4;
    const int c0 = n0 + wc * 64 + li;
    unsigned short* C = (unsigned short*)Cv;
    if (ROPEK && bn < 8) {
        const float sgn = (li & 1) ? 1.f : -1.f;
#pragma unroll
        for (int mi = 0; mi < 4; ++mi)
#pragma unroll
            for (int rr = 0; rr < 4; ++rr) {
                const int row = r0 + mi * 16 + rr;
                const int sidx = (row & (S_N - 1)) * 64;
#pragma unroll
                for (int ni = 0; ni < 4; ++ni) {
                    const int col = c0 + ni * 16;
                    const int ii = sidx + ((col & 127) >> 1);
                    float v = acc[mi][ni][rr];
                    float p = __shfl_xor(v, 1);
                    float o = v * fc[ii] + sgn * p * fs[ii];
                    C[(size_t)row * N + col] = f2bf(o);
                }
            }
    } else {
#pragma unroll
        for (int mi = 0; mi < 4; ++mi)
#pragma unroll
            for (int ni = 0; ni < 4; ++ni)
#pragma unroll
                for (int rr = 0; rr < 4; ++rr)
                    C[(size_t)(r0 + mi * 16 + rr) * N + c0 + ni * 16] = f2bf(acc[mi][ni][rr]);
    }
#undef STG2
#undef LDB2
#undef LDA2
#undef MFMA8
}

// ======= Flash attention v9 (R12, passed): GQA-fused 8-wave, register-P, defer-max =======
__device__ __forceinline__ void stage_k8(const unsigned short* kt_base,
                                         unsigned short* ks_base, int w, int lane) {
#pragma unroll
    for (int j = 0; j < 2; ++j) {
        int row = (w * 2 + j) * 4 + (lane >> 4);
        int colb = (lane & 15) * 16;
        int key = (row & 7) << 4;
        gl16(kt_base + (size_t)row * 2048 + ((colb ^ key) >> 1),
             ks_base + (w * 2 + j) * 512);
    }
}

__device__ __forceinline__ void load_v(const unsigned short* vt_base, int tid, uint4& a0, uint4& a1) {
    int kv = (tid >> 4) * 2, d0 = (tid & 15) * 8;
    const unsigned short* vp = vt_base + (size_t)kv * 2048 + d0;
    a0 = *(const uint4*)vp;
    a1 = *(const uint4*)(vp + 2048);
}

__device__ __forceinline__ void write_v(unsigned short* vt_lds, int tid, uint4 a0, uint4 a1) {
    int kv = (tid >> 4) * 2, d0 = (tid & 15) * 8;
    union { uint4 q; unsigned short u[8]; } x0, x1;
    x0.q = a0; x1.q = a1;
#pragma unroll
    for (int jj = 0; jj < 8; ++jj) {
        int d = d0 + jj;
        unsigned pack = (unsigned)x0.u[jj] | ((unsigned)x1.u[jj] << 16);
        int key = ((d ^ (d >> 3)) & 7) << 4;
        *(unsigned*)((char*)vt_lds + d * 128 + ((kv * 2) ^ key)) = pack;
    }
}

__global__ void __launch_bounds__(512, 2) attn_kernel(const unsigned short* __restrict__ Q,
                                                      const unsigned short* __restrict__ Kb,
                                                      const unsigned short* __restrict__ Vb,
                                                      unsigned short* __restrict__ O) {
    __shared__ unsigned short Ks[2][64 * 128];   // [kv][d], rows 256B
    __shared__ unsigned short Vt[2][128 * 64];   // [d][kv], rows 128B

    const int pidx = blockIdx.x;          // 0..15 pair index
    const int bg = blockIdx.y;            // b*8 + kvh
    const int b = bg >> 3, kvh = bg & 7;
    const int tid = threadIdx.x;
    const int w = tid >> 6, lane = tid & 63;
    const int li = lane & 15, lg = lane >> 4;
    const int h = kvh * 4 + (w >> 1);     // global head
    const int qh = (w & 1) * 32;          // q offset within 64-row tile

    const unsigned short* KVrow0 = Kb + (size_t)b * S_N * 2048 + kvh * 128;
    const unsigned short* Vrow0  = Vb + (size_t)b * S_N * 2048 + kvh * 128;

#pragma unroll 1
    for (int pass = 0; pass < 2; ++pass) {
        const int qt = pass ? (NQT - 1 - pidx) : pidx;
        const int nt = qt + 1;

        bf16x8 qf[2][4];
        {
            const unsigned short* qp = Q + ((size_t)b * S_N + qt * 64 + qh + li) * (H_N * HD_N)
                                         + h * HD_N + lg * 8;
#pragma unroll
            for (int mi = 0; mi < 2; ++mi)
#pragma unroll
                for (int ds = 0; ds < 4; ++ds)
                    qf[mi][ds] = *(const bf16x8*)(qp + (size_t)mi * 16 * (H_N * HD_N) + ds * 32);
        }

        float mreg[2], lreg[2];
#pragma unroll
        for (int mi = 0; mi < 2; ++mi) { mreg[mi] = -1e30f; lreg[mi] = 0.f; }
        f32x4 o_acc[2][8];
#pragma unroll
        for (int mi = 0; mi < 2; ++mi)
#pragma unroll
            for (int di = 0; di < 8; ++di) o_acc[mi][di] = (f32x4){0.f, 0.f, 0.f, 0.f};

        {
            stage_k8(KVrow0, &Ks[0][0], w, lane);
            uint4 a0, a1;
            load_v(Vrow0, tid, a0, a1);
            write_v(&Vt[0][0], tid, a0, a1);
        }
        __syncthreads();

#pragma unroll 1
        for (int t = 0; t < nt; ++t) {
            const int c = t & 1;
            const bool pre = (t + 1 < nt);
            uint4 a0, a1;
            if (pre) {
                stage_k8(KVrow0 + (size_t)(t + 1) * 64 * 2048, &Ks[c ^ 1][0], w, lane);
                load_v(Vrow0 + (size_t)(t + 1) * 64 * 2048, tid, a0, a1);
            }

            f32x4 sT[2][4];
#pragma unroll
            for (int mi = 0; mi < 2; ++mi)
#pragma unroll
                for (int ni = 0; ni < 4; ++ni) sT[mi][ni] = (f32x4){0.f, 0.f, 0.f, 0.f};
            __builtin_amdgcn_s_setprio(1);
#pragma unroll
            for (int ni = 0; ni < 4; ++ni) {
                const int kvc = ni * 16 + li;
                const int kkey = (kvc & 7) << 4;
                bf16x8 kf[4];
#pragma unroll
                for (int ds = 0; ds < 4; ++ds)
                    kf[ds] = *(const bf16x8*)((char*)&Ks[c][0] + kvc * 256
                                              + ((ds * 64 + lg * 16) ^ kkey));
#pragma unroll
                for (int mi = 0; mi < 2; ++mi)
#pragma unroll
                    for (int ds = 0; ds < 4; ++ds)
                        sT[mi][ni] = __builtin_amdgcn_mfma_f32_16x16x32_bf16(kf[ds], qf[mi][ds], sT[mi][ni], 0, 0, 0);
            }
            __builtin_amdgcn_s_setprio(0);

            if (t == qt) {
#pragma unroll
                for (int mi = 0; mi < 2; ++mi) {
                    int qq = qh + mi * 16 + li;
#pragma unroll
                    for (int ni = 0; ni < 4; ++ni)
#pragma unroll
                        for (int r = 0; r < 4; ++r)
                            if (ni * 16 + lg * 4 + r > qq) sT[mi][ni][r] = -1e30f;
                }
            }

            // ---- online softmax with defer-max ----
            float fac0[2];
            bool resc[2];
#pragma unroll
            for (int mi = 0; mi < 2; ++mi) {
                float pm = sT[mi][0][0];
#pragma unroll
                for (int ni = 0; ni < 4; ++ni)
#pragma unroll
                    for (int r = 0; r < 4; ++r) pm = fmaxf(pm, sT[mi][ni][r]);
                pm = fmaxf(pm, __shfl_xor(pm, 16));
                pm = fmaxf(pm, __shfl_xor(pm, 32));
                resc[mi] = !__all(pm <= mreg[mi] + 8.0f);
                fac0[mi] = 1.0f;
                if (resc[mi]) {
                    float mn = fmaxf(mreg[mi], pm);
                    fac0[mi] = __builtin_amdgcn_exp2f(mreg[mi] - mn);
                    mreg[mi] = mn;
                }
#pragma unroll
                for (int ni = 0; ni < 4; ++ni)
#pragma unroll
                    for (int r = 0; r < 4; ++r)
                        sT[mi][ni][r] = __builtin_amdgcn_exp2f(sT[mi][ni][r] - mreg[mi]);
                float rs = 0.f;
#pragma unroll
                for (int ni = 0; ni < 4; ++ni)
#pragma unroll
                    for (int r = 0; r < 4; ++r) rs += sT[mi][ni][r];
                rs += __shfl_xor(rs, 16);
                rs += __shfl_xor(rs, 32);
                lreg[mi] = lreg[mi] * fac0[mi] + rs;
            }

#pragma unroll
            for (int mi = 0; mi < 2; ++mi) {
                if (resc[mi]) {
                    float facR[4];
#pragma unroll
                    for (int rr = 0; rr < 4; ++rr)
                        facR[rr] = __shfl(fac0[mi], (lg << 4) | (lg * 4 + rr));
#pragma unroll
                    for (int di = 0; di < 8; ++di)
#pragma unroll
                        for (int rr = 0; rr < 4; ++rr) o_acc[mi][di][rr] *= facR[rr];
                }
            }

            union U { bf16x8 v; unsigned u[4]; };
            U pa[2][2];
#pragma unroll
            for (int mi = 0; mi < 2; ++mi)
#pragma unroll
                for (int ks = 0; ks < 2; ++ks) {
                    pa[mi][ks].u[0] = cvt_pk_bf16(sT[mi][2 * ks][0], sT[mi][2 * ks][1]);
                    pa[mi][ks].u[1] = cvt_pk_bf16(sT[mi][2 * ks][2], sT[mi][2 * ks][3]);
                    pa[mi][ks].u[2] = cvt_pk_bf16(sT[mi][2 * ks + 1][0], sT[mi][2 * ks + 1][1]);
                    pa[mi][ks].u[3] = cvt_pk_bf16(sT[mi][2 * ks + 1][2], sT[mi][2 * ks + 1][3]);
                }

            __builtin_amdgcn_s_setprio(1);
#pragma unroll
            for (int di = 0; di < 8; ++di) {
                int d = di * 16 + li;
                int vkey = ((d ^ (d >> 3)) & 7) << 4;
                const char* vbase = (const char*)&Vt[c][0] + d * 128;
                bf16x8 vf[2];
#pragma unroll
                for (int ks = 0; ks < 2; ++ks) {
                    union { bf16x8 v; unsigned long long g[2]; } vv;
                    int cb = ks * 64 + lg * 8;
                    vv.g[0] = *(const unsigned long long*)(vbase + (cb ^ vkey));
                    vv.g[1] = *(const unsigned long long*)(vbase + ((cb + 32) ^ vkey));
                    vf[ks] = vv.v;
                }
#pragma unroll
                for (int mi = 0; mi < 2; ++mi)
#pragma unroll
                    for (int ks = 0; ks < 2; ++ks)
                        o_acc[mi][di] = __builtin_amdgcn_mfma_f32_16x16x32_bf16(pa[mi][ks].v, vf[ks], o_acc[mi][di], 0, 0, 0);
            }
            __builtin_amdgcn_s_setprio(0);

            if (pre) write_v(&Vt[c ^ 1][0], tid, a0, a1);
            __syncthreads();
        }

        unsigned short* op = O + ((size_t)b * S_N + qt * 64 + qh + lg * 4) * (H_N * HD_N)
                               + h * HD_N + li;
#pragma unroll
        for (int mi = 0; mi < 2; ++mi) {
            float iv = 1.f / lreg[mi];
            float ivR[4];
#pragma unroll
            for (int rr = 0; rr < 4; ++rr)
                ivR[rr] = __shfl(iv, (lg << 4) | (lg * 4 + rr));
#pragma unroll
            for (int di = 0; di < 8; ++di)
#pragma unroll
                for (int rr = 0; rr < 4; ++rr)
                    op[((size_t)(mi * 16 + rr)) * (H_N * HD_N) + di * 16]
                        = f2bf(o_acc[mi][di][rr] * ivR[rr]);
        }
    }
}

// ---------------- launch ----------------
extern "C" void kernel_launch(void* const* d_in, const int* in_sizes, int n_in,
                              void* d_out, int out_size, void* d_ws, size_t ws_size,
                              hipStream_t stream) {
    (void)in_sizes; (void)n_in; (void)out_size; (void)ws_size;
    const float* x  = (const float*)d_in[0];
    const float* wq = (const float*)d_in[1];
    const float* wk = (const float*)d_in[2];
    const float* wv = (const float*)d_in[3];
    const float* wo = (const float*)d_in[4];
    const float* fc = (const float*)d_in[5];
    const float* fs = (const float*)d_in[6];
    float* out = (float*)d_out;

    char* ws = (char*)d_ws;
    unsigned short* xb  = (unsigned short*)(ws);                // 33.5MB  x bf16
    unsigned short* wb  = (unsigned short*)(ws + 33554432);     // 33.5MB  wq, later wo
    unsigned short* wkv = (unsigned short*)(ws + 67108864);     // 16.8MB  [wk;wv]
    unsigned short* Qb  = (unsigned short*)(ws + 83886080);     // 33.5MB  Q, later attn-O
    unsigned short* KVb = (unsigned short*)(ws + 117440512);    // 16.8MB  [K|V] rows of 2048

    const int BS = B_N * S_N;  // 4096

    // fused f32->bf16: x|wq|wk|wv -> xb|wb|wkv
    conv_multi<<<dim3(41943040u / 1024), 256, 0, stream>>>(x, wq, wk, wv, xb);

    // Q = rope(x wq^T) * QS_LOG2E  (bf16 out, fused RoPE epilogue)
    gemm256<2><<<dim3((BS / 256) * (D_N / 256)), 512, 0, stream>>>(xb, wb, Qb, BS, D_N, D_N, fc, fs);
    conv_f32_bf16<<<dim3(D_N * H_N * HD_N / 1024), 256, 0, stream>>>(wo, wb);
    // [K|V] = x [wk;wv]^T, 256x128 tile (grid 256), RoPE fused on K columns
    gemm256x128<1><<<dim3((BS / 256) * (2048 / 128)), 512, 0, stream>>>(xb, wkv, KVb, BS, 2048, D_N, fc, fs);

    // attention: GQA-fused 256 blocks (1/CU), 8 waves, register-P, defer-max
    attn_kernel<<<dim3(NQT / 2, B_N * KVH_N), 512, 0, stream>>>(Qb, KVb, KVb + 1024, Qb);

    // out = O wo^T (f32 out)
    gemm256<1><<<dim3((BS / 256) * (D_N / 256)), 512, 0, stream>>>(Qb, wb, out, BS, D_N, D_N, fc, fs);
}

// Round 15
// 524.339 us; speedup vs baseline: 1.0006x; 1.0006x over previous
//
#include <hip/hip_runtime.h>
#include <stdint.h>

#define B_N 2
#define S_N 2048
#define D_N 4096
#define H_N 32
#define KVH_N 8
#define HD_N 128
#define NQT (S_N / 64)
// 1/sqrt(128) * log2(e)  (Q prescale; softmax runs in exp2 domain)
#define QS_LOG2E 0.12751743f

typedef __attribute__((ext_vector_type(8))) short bf16x8;
typedef __attribute__((ext_vector_type(4))) float f32x4;

__device__ __forceinline__ unsigned short f2bf(float f) {
    union { float f; unsigned u; } v; v.f = f;
    unsigned u = v.u;
    u += 0x7fffu + ((u >> 16) & 1u);   // RNE
    return (unsigned short)(u >> 16);
}
__device__ __forceinline__ float bf2f(unsigned short h) {
    union { unsigned u; float f; } v; v.u = ((unsigned)h) << 16;
    return v.f;
}
__device__ __forceinline__ unsigned cvt_pk_bf16(float lo, float hi) {
    unsigned r;
    asm("v_cvt_pk_bf16_f32 %0, %1, %2" : "=v"(r) : "v"(lo), "v"(hi));
    return r;
}

__device__ __forceinline__ void gl16(const unsigned short* g, unsigned short* l) {
    __builtin_amdgcn_global_load_lds(
        (const __attribute__((address_space(1))) void*)g,
        (__attribute__((address_space(3))) void*)l, 16, 0, 0);
}

// ---------------- f32 -> bf16 conversion ----------------
__global__ void __launch_bounds__(256) conv_f32_bf16(const float* __restrict__ in,
                                                     unsigned short* __restrict__ out) {
    int i = (blockIdx.x * 256 + threadIdx.x) * 4;
    float4 v = *(const float4*)(in + i);
    ushort4 o;
    o.x = f2bf(v.x); o.y = f2bf(v.y); o.z = f2bf(v.z); o.w = f2bf(v.w);
    *(ushort4*)(out + i) = o;
}

// Fused x|wq|wk|wv -> contiguous bf16 workspace (xb|wb|wkv).
__global__ void __launch_bounds__(256) conv_multi(const float* __restrict__ x,
                                                  const float* __restrict__ wq,
                                                  const float* __restrict__ wk,
                                                  const float* __restrict__ wv,
                                                  unsigned short* __restrict__ dst) {
    size_t i = ((size_t)blockIdx.x * 256 + threadIdx.x) * 4;
    const float* s;
    if (i < 16777216u)      s = x  + i;
    else if (i < 33554432u) s = wq + (i - 16777216u);
    else if (i < 37748736u) s = wk + (i - 33554432u);
    else                    s = wv + (i - 37748736u);
    float4 v = *(const float4*)s;
    ushort4 o;
    o.x = f2bf(v.x); o.y = f2bf(v.y); o.z = f2bf(v.z); o.w = f2bf(v.w);
    *(ushort4*)(dst + i) = o;
}

// ========== 256x256 8-phase NT GEMM (R9-R12 proven schedule, 16x16x32 MFMA) ==========
// MODE: 0 = bf16 out, 1 = f32 out, 2 = bf16 out + fused RoPE(Q) * QS_LOG2E.
#define BAR() __builtin_amdgcn_s_barrier()
#define VMC4() asm volatile("s_waitcnt vmcnt(4)" ::: "memory")
#define VMC2() asm volatile("s_waitcnt vmcnt(2)" ::: "memory")

template<int MODE>
__global__ void __launch_bounds__(512, 2)
gemm256(const unsigned short* __restrict__ A, const unsigned short* __restrict__ Bm,
        void* __restrict__ Cv, int M, int N, int K,
        const float* __restrict__ fc, const float* __restrict__ fs) {
    __shared__ unsigned short ldsA[2][16384];
    __shared__ unsigned short ldsB[2][16384];

    const int tid = threadIdx.x;
    const int lane = tid & 63;
    const int w = tid >> 6;
    const int li = lane & 15, lg = lane >> 4;
    const int wr = w >> 2, wc = w & 3;

    const int nwg = gridDim.x;
    const int cpx = nwg >> 3;
    const int wg = (blockIdx.x & 7) * cpx + (blockIdx.x >> 3);
    const int nbn = N >> 8;
    const int bm = wg / nbn, bn = wg - bm * nbn;
    const int m0 = bm << 8, n0 = bn << 8;

    const int rbase = ((tid >> 7) << 4) + ((tid >> 2) & 15);
    const int cstg = ((tid >> 6) & 1) * 32 + (((tid & 3) * 8) ^ (((tid >> 5) & 1) << 4));
    const unsigned short* Abase = A + (size_t)(m0 + rbase) * K + cstg;
    const unsigned short* Bbase = Bm + (size_t)(n0 + rbase) * K + cstg;
    const int dstoff = tid * 8;
    const int kmask = K - 1;

    f32x4 acc[8][4];
#pragma unroll
    for (int i = 0; i < 8; ++i)
#pragma unroll
        for (int j = 0; j < 4; ++j) acc[i][j] = (f32x4){0.f, 0.f, 0.f, 0.f};

    const int colpart = (lg * 16) ^ ((li >> 3) << 5);

#define STG(BASE, LDSBUF, H, T) do {                                              \
        int kk_ = ((T) * 64) & kmask;                                             \
        gl16(BASE + (size_t)(((H) * 2 + 0) * 64) * K + kk_,                       \
             &LDSBUF[((H) * 2 + 0) * 4096 + dstoff]);                             \
        gl16(BASE + (size_t)(((H) * 2 + 1) * 64) * K + kk_,                       \
             &LDSBUF[((H) * 2 + 1) * 4096 + dstoff]);                             \
    } while (0)

#define LDBs(set, buf) do {                                                       \
        _Pragma("unroll")                                                         \
        for (int ni_ = 0; ni_ < 4; ++ni_) {                                       \
            _Pragma("unroll")                                                     \
            for (int ks_ = 0; ks_ < 2; ++ks_)                                     \
                bfr[set][ni_][ks_] = *(const bf16x8*)((const char*)&ldsB[buf][0]  \
                    + (wc * 4 + ni_) * 2048 + ks_ * 1024 + li * 64 + colpart);    \
        }                                                                         \
    } while (0)

#define LDAs(set, buf, q) do {                                                    \
        _Pragma("unroll")                                                         \
        for (int m_ = 0; m_ < 2; ++m_) {                                          \
            _Pragma("unroll")                                                     \
            for (int ks_ = 0; ks_ < 2; ++ks_)                                     \
                af[set][m_][ks_] = *(const bf16x8*)((const char*)&ldsA[buf][0]    \
                    + (wr * 8 + (q) * 2 + m_) * 2048 + ks_ * 1024 + li * 64 + colpart); \
        }                                                                         \
    } while (0)

#define MFMAs(sb, sa, q) do {                                                     \
        __builtin_amdgcn_s_setprio(1);                                            \
        _Pragma("unroll")                                                         \
        for (int ks_ = 0; ks_ < 2; ++ks_) {                                       \
            _Pragma("unroll")                                                     \
            for (int m_ = 0; m_ < 2; ++m_) {                                      \
                _Pragma("unroll")                                                 \
                for (int ni_ = 0; ni_ < 4; ++ni_)                                 \
                    acc[(q) * 2 + m_][ni_] = __builtin_amdgcn_mfma_f32_16x16x32_bf16( \
                        af[sa][m_][ks_], bfr[sb][ni_][ks_], acc[(q) * 2 + m_][ni_], 0, 0, 0); \
            }                                                                     \
        }                                                                         \
        __builtin_amdgcn_s_setprio(0);                                            \
    } while (0)

    STG(Abase, ldsA[0], 0, 0); STG(Abase, ldsA[0], 1, 0);
    STG(Bbase, ldsB[0], 0, 0); STG(Bbase, ldsB[0], 1, 0);
    STG(Bbase, ldsB[1], 0, 1); STG(Bbase, ldsB[1], 1, 1);
    VMC4();
    BAR();

    bf16x8 bfr[2][4][2], af[2][2][2];
    LDBs(0, 0);
    LDAs(0, 0, 0);

    const int NIT = K >> 7;
#pragma unroll 1
    for (int i = 0; i < NIT; ++i) {
        const int T = 2 * i;
        LDAs(1, 0, 1);
        STG(Abase, ldsA[1], 0, T + 1);
        MFMAs(0, 0, 0);
        BAR();
        LDAs(0, 0, 2);
        STG(Abase, ldsA[1], 1, T + 1);
        STG(Bbase, ldsB[0], 0, T + 2);
        MFMAs(0, 1, 1);
        BAR();
        LDAs(1, 0, 3);
        STG(Bbase, ldsB[0], 1, T + 2);
        MFMAs(0, 0, 2);
        VMC4();
        BAR();
        LDBs(1, 1);
        LDAs(0, 1, 0);
        MFMAs(0, 1, 3);
        BAR();
        LDAs(1, 1, 1);
        STG(Abase, ldsA[0], 0, T + 2);
        MFMAs(1, 0, 0);
        BAR();
        LDAs(0, 1, 2);
        STG(Abase, ldsA[0], 1, T + 2);
        STG(Bbase, ldsB[1], 0, T + 3);
        MFMAs(1, 1, 1);
        BAR();
        LDAs(1, 1, 3);
        STG(Bbase, ldsB[1], 1, T + 3);
        MFMAs(1, 0, 2);
        VMC4();
        BAR();
        LDBs(0, 0);
        LDAs(0, 0, 0);
        MFMAs(1, 1, 3);
        BAR();
    }

    const int r0 = m0 + wr * 128 + lg * 4;
    const int c0 = n0 + wc * 64 + li;
    if (MODE == 1) {
        float* C = (float*)Cv;
#pragma unroll
        for (int mi = 0; mi < 8; ++mi)
#pragma unroll
            for (int ni = 0; ni < 4; ++ni)
#pragma unroll
                for (int rr = 0; rr < 4; ++rr)
                    C[(size_t)(r0 + mi * 16 + rr) * N + c0 + ni * 16] = acc[mi][ni][rr];
    } else if (MODE == 0) {
        unsigned short* C = (unsigned short*)Cv;
#pragma unroll
        for (int mi = 0; mi < 8; ++mi)
#pragma unroll
            for (int ni = 0; ni < 4; ++ni)
#pragma unroll
                for (int rr = 0; rr < 4; ++rr)
                    C[(size_t)(r0 + mi * 16 + rr) * N + c0 + ni * 16] = f2bf(acc[mi][ni][rr]);
    } else {
        // fused RoPE(Q) + QS_LOG2E prescale
        unsigned short* C = (unsigned short*)Cv;
        const float sgn = (li & 1) ? 1.f : -1.f;
#pragma unroll
        for (int mi = 0; mi < 8; ++mi)
#pragma unroll
            for (int rr = 0; rr < 4; ++rr) {
                const int row = r0 + mi * 16 + rr;
                const int sidx = (row & (S_N - 1)) * 64;
#pragma unroll
                for (int ni = 0; ni < 4; ++ni) {
                    const int col = c0 + ni * 16;
                    const int ii = sidx + ((col & 127) >> 1);
                    float v = acc[mi][ni][rr];
                    float p = __shfl_xor(v, 1);
                    float o = (v * fc[ii] + sgn * p * fs[ii]) * QS_LOG2E;
                    C[(size_t)row * N + col] = f2bf(o);
                }
            }
    }
#undef STG
#undef LDBs
#undef LDAs
#undef MFMAs
}

// ========================= 256x128 8-phase NT GEMM (R10-R12 proven) =========
template<int ROPEK>
__global__ void __launch_bounds__(512, 2)
gemm256x128(const unsigned short* __restrict__ A, const unsigned short* __restrict__ Bm,
            void* __restrict__ Cv, int M, int N, int K,
            const float* __restrict__ fc, const float* __restrict__ fs) {
    __shared__ unsigned short ldsA[2][16384];
    __shared__ unsigned short ldsB[2][8192];

    const int tid = threadIdx.x;
    const int lane = tid & 63;
    const int w = tid >> 6;
    const int li = lane & 15, lg = lane >> 4;
    const int wr = w >> 1, wc = w & 1;

    const int nwg = gridDim.x;
    const int cpx = nwg >> 3;
    const int wg = (blockIdx.x & 7) * cpx + (blockIdx.x >> 3);
    const int nbn = N >> 7;
    const int bm = wg / nbn, bn = wg - bm * nbn;
    const int m0 = bm << 8, n0 = bn << 7;

    const int rbase = ((tid >> 7) << 4) + ((tid >> 2) & 15);
    const int cstg = ((tid >> 6) & 1) * 32 + (((tid & 3) * 8) ^ (((tid >> 5) & 1) << 4));
    const unsigned short* Asrc[4];
    const unsigned short* Bsrc[2];
#pragma unroll
    for (int hj = 0; hj < 4; ++hj)
        Asrc[hj] = A + (size_t)(m0 + hj * 64 + rbase) * K + cstg;
#pragma unroll
    for (int hj = 0; hj < 2; ++hj)
        Bsrc[hj] = Bm + (size_t)(n0 + hj * 64 + rbase) * K + cstg;
    const int dstoff = tid * 8;
    const int kmask = K - 1;

    f32x4 acc[4][4];
#pragma unroll
    for (int i = 0; i < 4; ++i)
#pragma unroll
        for (int j = 0; j < 4; ++j) acc[i][j] = (f32x4){0.f, 0.f, 0.f, 0.f};

    const int colpart = (lg * 16) ^ ((li >> 3) << 5);

#define STG2(SRC, LDSBUF, H, T) do {                                        \
        int kk_ = ((T) * 64) & kmask;                                       \
        gl16(SRC[(H)*2 + 0] + kk_, &LDSBUF[((H)*2 + 0) * 4096 + dstoff]);   \
        gl16(SRC[(H)*2 + 1] + kk_, &LDSBUF[((H)*2 + 1) * 4096 + dstoff]);   \
    } while (0)

#define LDB2(buf) do {                                                       \
        _Pragma("unroll")                                                    \
        for (int ni_ = 0; ni_ < 4; ++ni_) {                                  \
            _Pragma("unroll")                                                \
            for (int ks_ = 0; ks_ < 2; ++ks_)                                \
                bfr[ni_][ks_] = *(const bf16x8*)((const char*)&ldsB[buf][0]  \
                    + (wc * 4 + ni_) * 2048 + ks_ * 1024 + li * 64 + colpart); \
        }                                                                    \
    } while (0)

#define LDA2(buf, q) do {                                                    \
        _Pragma("unroll")                                                    \
        for (int ks_ = 0; ks_ < 2; ++ks_)                                    \
            af2[ks_] = *(const bf16x8*)((const char*)&ldsA[buf][0]           \
                + (wr * 4 + (q)) * 2048 + ks_ * 1024 + li * 64 + colpart);   \
    } while (0)

#define MFMA8(q) do {                                                        \
        __builtin_amdgcn_s_setprio(1);                                       \
        _Pragma("unroll")                                                    \
        for (int ks_ = 0; ks_ < 2; ++ks_) {                                  \
            _Pragma("unroll")                                                \
            for (int ni_ = 0; ni_ < 4; ++ni_)                                \
                acc[q][ni_] = __builtin_amdgcn_mfma_f32_16x16x32_bf16(       \
                    af2[ks_], bfr[ni_][ks_], acc[q][ni_], 0, 0, 0);          \
        }                                                                    \
        __builtin_amdgcn_s_setprio(0);                                       \
    } while (0)

    STG2(Asrc, ldsA[0], 0, 0); STG2(Asrc, ldsA[0], 1, 0);
    STG2(Bsrc, ldsB[0], 0, 0);
    STG2(Bsrc, ldsB[1], 0, 1);
    VMC2();
    BAR();

    const int NIT = K >> 7;
    bf16x8 bfr[4][2], af2[2];
#pragma unroll 1
    for (int i = 0; i < NIT; ++i) {
        const int T = 2 * i;
        LDB2(0); LDA2(0, 0);
        STG2(Asrc, ldsA[1], 0, T + 1);
        BAR(); MFMA8(0); BAR();
        LDA2(0, 1);
        STG2(Asrc, ldsA[1], 1, T + 1);
        BAR(); MFMA8(1); BAR();
        LDA2(0, 2);
        STG2(Bsrc, ldsB[0], 0, T + 2);
        BAR(); MFMA8(2); BAR();
        LDA2(0, 3);
        VMC2();
        BAR(); MFMA8(3); BAR();
        LDB2(1); LDA2(1, 0);
        STG2(Asrc, ldsA[0], 0, T + 2);
        BAR(); MFMA8(0); BAR();
        LDA2(1, 1);
        STG2(Asrc, ldsA[0], 1, T + 2);
        BAR(); MFMA8(1); BAR();
        LDA2(1, 2);
        STG2(Bsrc, ldsB[1], 0, T + 3);
        BAR(); MFMA8(2); BAR();
        LDA2(1, 3);
        VMC2();
        BAR(); MFMA8(3); BAR();
    }

    const int r0 = m0 + wr * 64 + lg * 4;
    const int c0 = n0 + wc * 64 + li;
    unsigned short* C = (unsigned short*)Cv;
    if (ROPEK && bn < 8) {
        const float sgn = (li & 1) ? 1.f : -1.f;
#pragma unroll
        for (int mi = 0; mi < 4; ++mi)
#pragma unroll
            for (int rr = 0; rr < 4; ++rr) {
                const int row = r0 + mi * 16 + rr;
                const int sidx = (row & (S_N - 1)) * 64;
#pragma unroll
                for (int ni = 0; ni < 4; ++ni) {
                    const int col = c0 + ni * 16;
                    const int ii = sidx + ((col & 127) >> 1);
                    float v = acc[mi][ni][rr];
                    float p = __shfl_xor(v, 1);
                    float o = v * fc[ii] + sgn * p * fs[ii];
                    C[(size_t)row * N + col] = f2bf(o);
                }
            }
    } else {
#pragma unroll
        for (int mi = 0; mi < 4; ++mi)
#pragma unroll
            for (int ni = 0; ni < 4; ++ni)
#pragma unroll
                for (int rr = 0; rr < 4; ++rr)
                    C[(size_t)(r0 + mi * 16 + rr) * N + c0 + ni * 16] = f2bf(acc[mi][ni][rr]);
    }
#undef STG2
#undef LDB2
#undef LDA2
#undef MFMA8
}

// ======= Flash attention v9 (R12, passed): GQA-fused 8-wave, register-P, defer-max =======
__device__ __forceinline__ void stage_k8(const unsigned short* kt_base,
                                         unsigned short* ks_base, int w, int lane) {
#pragma unroll
    for (int j = 0; j < 2; ++j) {
        int row = (w * 2 + j) * 4 + (lane >> 4);
        int colb = (lane & 15) * 16;
        int key = (row & 7) << 4;
        gl16(kt_base + (size_t)row * 2048 + ((colb ^ key) >> 1),
             ks_base + (w * 2 + j) * 512);
    }
}

__device__ __forceinline__ void load_v(const unsigned short* vt_base, int tid, uint4& a0, uint4& a1) {
    int kv = (tid >> 4) * 2, d0 = (tid & 15) * 8;
    const unsigned short* vp = vt_base + (size_t)kv * 2048 + d0;
    a0 = *(const uint4*)vp;
    a1 = *(const uint4*)(vp + 2048);
}

__device__ __forceinline__ void write_v(unsigned short* vt_lds, int tid, uint4 a0, uint4 a1) {
    int kv = (tid >> 4) * 2, d0 = (tid & 15) * 8;
    union { uint4 q; unsigned short u[8]; } x0, x1;
    x0.q = a0; x1.q = a1;
#pragma unroll
    for (int jj = 0; jj < 8; ++jj) {
        int d = d0 + jj;
        unsigned pack = (unsigned)x0.u[jj] | ((unsigned)x1.u[jj] << 16);
        int key = ((d ^ (d >> 3)) & 7) << 4;
        *(unsigned*)((char*)vt_lds + d * 128 + ((kv * 2) ^ key)) = pack;
    }
}

__global__ void __launch_bounds__(512, 2) attn_kernel(const unsigned short* __restrict__ Q,
                                                      const unsigned short* __restrict__ Kb,
                                                      const unsigned short* __restrict__ Vb,
                                                      unsigned short* __restrict__ O) {
    __shared__ unsigned short Ks[2][64 * 128];   // [kv][d], rows 256B
    __shared__ unsigned short Vt[2][128 * 64];   // [d][kv], rows 128B

    const int pidx = blockIdx.x;          // 0..15 pair index
    const int bg = blockIdx.y;            // b*8 + kvh
    const int b = bg >> 3, kvh = bg & 7;
    const int tid = threadIdx.x;
    const int w = tid >> 6, lane = tid & 63;
    const int li = lane & 15, lg = lane >> 4;
    const int h = kvh * 4 + (w >> 1);     // global head
    const int qh = (w & 1) * 32;          // q offset within 64-row tile

    const unsigned short* KVrow0 = Kb + (size_t)b * S_N * 2048 + kvh * 128;
    const unsigned short* Vrow0  = Vb + (size_t)b * S_N * 2048 + kvh * 128;

#pragma unroll 1
    for (int pass = 0; pass < 2; ++pass) {
        const int qt = pass ? (NQT - 1 - pidx) : pidx;
        const int nt = qt + 1;

        bf16x8 qf[2][4];
        {
            const unsigned short* qp = Q + ((size_t)b * S_N + qt * 64 + qh + li) * (H_N * HD_N)
                                         + h * HD_N + lg * 8;
#pragma unroll
            for (int mi = 0; mi < 2; ++mi)
#pragma unroll
                for (int ds = 0; ds < 4; ++ds)
                    qf[mi][ds] = *(const bf16x8*)(qp + (size_t)mi * 16 * (H_N * HD_N) + ds * 32);
        }

        float mreg[2], lreg[2];
#pragma unroll
        for (int mi = 0; mi < 2; ++mi) { mreg[mi] = -1e30f; lreg[mi] = 0.f; }
        f32x4 o_acc[2][8];
#pragma unroll
        for (int mi = 0; mi < 2; ++mi)
#pragma unroll
            for (int di = 0; di < 8; ++di) o_acc[mi][di] = (f32x4){0.f, 0.f, 0.f, 0.f};

        {
            stage_k8(KVrow0, &Ks[0][0], w, lane);
            uint4 a0, a1;
            load_v(Vrow0, tid, a0, a1);
            write_v(&Vt[0][0], tid, a0, a1);
        }
        __syncthreads();

#pragma unroll 1
        for (int t = 0; t < nt; ++t) {
            const int c = t & 1;
            const bool pre = (t + 1 < nt);
            uint4 a0, a1;
            if (pre) {
                stage_k8(KVrow0 + (size_t)(t + 1) * 64 * 2048, &Ks[c ^ 1][0], w, lane);
                load_v(Vrow0 + (size_t)(t + 1) * 64 * 2048, tid, a0, a1);
            }

            f32x4 sT[2][4];
#pragma unroll
            for (int mi = 0; mi < 2; ++mi)
#pragma unroll
                for (int ni = 0; ni < 4; ++ni) sT[mi][ni] = (f32x4){0.f, 0.f, 0.f, 0.f};
            __builtin_amdgcn_s_setprio(1);
#pragma unroll
            for (int ni = 0; ni < 4; ++ni) {
                const int kvc = ni * 16 + li;
                const int kkey = (kvc & 7) << 4;
                bf16x8 kf[4];
#pragma unroll
                for (int ds = 0; ds < 4; ++ds)
                    kf[ds] = *(const bf16x8*)((char*)&Ks[c][0] + kvc * 256
                                              + ((ds * 64 + lg * 16) ^ kkey));
#pragma unroll
                for (int mi = 0; mi < 2; ++mi)
#pragma unroll
                    for (int ds = 0; ds < 4; ++ds)
                        sT[mi][ni] = __builtin_amdgcn_mfma_f32_16x16x32_bf16(kf[ds], qf[mi][ds], sT[mi][ni], 0, 0, 0);
            }
            __builtin_amdgcn_s_setprio(0);

            if (t == qt) {
#pragma unroll
                for (int mi = 0; mi < 2; ++mi) {
                    int qq = qh + mi * 16 + li;
#pragma unroll
                    for (int ni = 0; ni < 4; ++ni)
#pragma unroll
                        for (int r = 0; r < 4; ++r)
                            if (ni * 16 + lg * 4 + r > qq) sT[mi][ni][r] = -1e30f;
                }
            }

            // ---- online softmax with defer-max ----
            float fac0[2];
            bool resc[2];
#pragma unroll
            for (int mi = 0; mi < 2; ++mi) {
                float pm = sT[mi][0][0];
#pragma unroll
                for (int ni = 0; ni < 4; ++ni)
#pragma unroll
                    for (int r = 0; r < 4; ++r) pm = fmaxf(pm, sT[mi][ni][r]);
                pm = fmaxf(pm, __shfl_xor(pm, 16));
                pm = fmaxf(pm, __shfl_xor(pm, 32));
                resc[mi] = !__all(pm <= mreg[mi] + 8.0f);
                fac0[mi] = 1.0f;
                if (resc[mi]) {
                    float mn = fmaxf(mreg[mi], pm);
                    fac0[mi] = __builtin_amdgcn_exp2f(mreg[mi] - mn);
                    mreg[mi] = mn;
                }
#pragma unroll
                for (int ni = 0; ni < 4; ++ni)
#pragma unroll
                    for (int r = 0; r < 4; ++r)
                        sT[mi][ni][r] = __builtin_amdgcn_exp2f(sT[mi][ni][r] - mreg[mi]);
                float rs = 0.f;
#pragma unroll
                for (int ni = 0; ni < 4; ++ni)
#pragma unroll
                    for (int r = 0; r < 4; ++r) rs += sT[mi][ni][r];
                rs += __shfl_xor(rs, 16);
                rs += __shfl_xor(rs, 32);
                lreg[mi] = lreg[mi] * fac0[mi] + rs;
            }

#pragma unroll
            for (int mi = 0; mi < 2; ++mi) {
                if (resc[mi]) {
                    float facR[4];
#pragma unroll
                    for (int rr = 0; rr < 4; ++rr)
                        facR[rr] = __shfl(fac0[mi], (lg << 4) | (lg * 4 + rr));
#pragma unroll
                    for (int di = 0; di < 8; ++di)
#pragma unroll
                        for (int rr = 0; rr < 4; ++rr) o_acc[mi][di][rr] *= facR[rr];
                }
            }

            union U { bf16x8 v; unsigned u[4]; };
            U pa[2][2];
#pragma unroll
            for (int mi = 0; mi < 2; ++mi)
#pragma unroll
                for (int ks = 0; ks < 2; ++ks) {
                    pa[mi][ks].u[0] = cvt_pk_bf16(sT[mi][2 * ks][0], sT[mi][2 * ks][1]);
                    pa[mi][ks].u[1] = cvt_pk_bf16(sT[mi][2 * ks][2], sT[mi][2 * ks][3]);
                    pa[mi][ks].u[2] = cvt_pk_bf16(sT[mi][2 * ks + 1][0], sT[mi][2 * ks + 1][1]);
                    pa[mi][ks].u[3] = cvt_pk_bf16(sT[mi][2 * ks + 1][2], sT[mi][2 * ks + 1][3]);
                }

            __builtin_amdgcn_s_setprio(1);
#pragma unroll
            for (int di = 0; di < 8; ++di) {
                int d = di * 16 + li;
                int vkey = ((d ^ (d >> 3)) & 7) << 4;
                const char* vbase = (const char*)&Vt[c][0] + d * 128;
                bf16x8 vf[2];
#pragma unroll
                for (int ks = 0; ks < 2; ++ks) {
                    union { bf16x8 v; unsigned long long g[2]; } vv;
                    int cb = ks * 64 + lg * 8;
                    vv.g[0] = *(const unsigned long long*)(vbase + (cb ^ vkey));
                    vv.g[1] = *(const unsigned long long*)(vbase + ((cb + 32) ^ vkey));
                    vf[ks] = vv.v;
                }
#pragma unroll
                for (int mi = 0; mi < 2; ++mi)
#pragma unroll
                    for (int ks = 0; ks < 2; ++ks)
                        o_acc[mi][di] = __builtin_amdgcn_mfma_f32_16x16x32_bf16(pa[mi][ks].v, vf[ks], o_acc[mi][di], 0, 0, 0);
            }
            __builtin_amdgcn_s_setprio(0);

            if (pre) write_v(&Vt[c ^ 1][0], tid, a0, a1);
            __syncthreads();
        }

        unsigned short* op = O + ((size_t)b * S_N + qt * 64 + qh + lg * 4) * (H_N * HD_N)
                               + h * HD_N + li;
#pragma unroll
        for (int mi = 0; mi < 2; ++mi) {
            float iv = 1.f / lreg[mi];
            float ivR[4];
#pragma unroll
            for (int rr = 0; rr < 4; ++rr)
                ivR[rr] = __shfl(iv, (lg << 4) | (lg * 4 + rr));
#pragma unroll
            for (int di = 0; di < 8; ++di)
#pragma unroll
                for (int rr = 0; rr < 4; ++rr)
                    op[((size_t)(mi * 16 + rr)) * (H_N * HD_N) + di * 16]
                        = f2bf(o_acc[mi][di][rr] * ivR[rr]);
        }
    }
}

// ---------------- launch ----------------
extern "C" void kernel_launch(void* const* d_in, const int* in_sizes, int n_in,
                              void* d_out, int out_size, void* d_ws, size_t ws_size,
                              hipStream_t stream) {
    (void)in_sizes; (void)n_in; (void)out_size; (void)ws_size;
    const float* x  = (const float*)d_in[0];
    const float* wq = (const float*)d_in[1];
    const float* wk = (const float*)d_in[2];
    const float* wv = (const float*)d_in[3];
    const float* wo = (const float*)d_in[4];
    const float* fc = (const float*)d_in[5];
    const float* fs = (const float*)d_in[6];
    float* out = (float*)d_out;

    char* ws = (char*)d_ws;
    unsigned short* xb  = (unsigned short*)(ws);                // 33.5MB  x bf16
    unsigned short* wb  = (unsigned short*)(ws + 33554432);     // 33.5MB  wq, later wo
    unsigned short* wkv = (unsigned short*)(ws + 67108864);     // 16.8MB  [wk;wv]
    unsigned short* Qb  = (unsigned short*)(ws + 83886080);     // 33.5MB  Q, later attn-O
    unsigned short* KVb = (unsigned short*)(ws + 117440512);    // 16.8MB  [K|V] rows of 2048

    const int BS = B_N * S_N;  // 4096

    // fused f32->bf16: x|wq|wk|wv -> xb|wb|wkv
    conv_multi<<<dim3(41943040u / 1024), 256, 0, stream>>>(x, wq, wk, wv, xb);

    // Q = rope(x wq^T) * QS_LOG2E  (bf16 out, fused RoPE epilogue)
    gemm256<2><<<dim3((BS / 256) * (D_N / 256)), 512, 0, stream>>>(xb, wb, Qb, BS, D_N, D_N, fc, fs);
    conv_f32_bf16<<<dim3(D_N * H_N * HD_N / 1024), 256, 0, stream>>>(wo, wb);
    // [K|V] = x [wk;wv]^T, 256x128 tile (grid 256), RoPE fused on K columns
    gemm256x128<1><<<dim3((BS / 256) * (2048 / 128)), 512, 0, stream>>>(xb, wkv, KVb, BS, 2048, D_N, fc, fs);

    // attention: GQA-fused 256 blocks (1/CU), 8 waves, register-P, defer-max
    attn_kernel<<<dim3(NQT / 2, B_N * KVH_N), 512, 0, stream>>>(Qb, KVb, KVb + 1024, Qb);

    // out = O wo^T (f32 out)
    gemm256<1><<<dim3((BS / 256) * (D_N / 256)), 512, 0, stream>>>(Qb, wb, out, BS, D_N, D_N, fc, fs);
}

// Round 16
// 523.058 us; speedup vs baseline: 1.0030x; 1.0025x over previous
//
#include <hip/hip_runtime.h>
#include <stdint.h>

#define B_N 2
#define S_N 2048
#define D_N 4096
#define H_N 32
#define KVH_N 8
#define HD_N 128
#define NQT (S_N / 64)
// 1/sqrt(128) * log2(e)  (Q prescale; softmax runs in exp2 domain)
#define QS_LOG2E 0.12751743f

typedef __attribute__((ext_vector_type(8))) short bf16x8;
typedef __attribute__((ext_vector_type(4))) float f32x4;

__device__ __forceinline__ unsigned short f2bf(float f) {
    union { float f; unsigned u; } v; v.f = f;
    unsigned u = v.u;
    u += 0x7fffu + ((u >> 16) & 1u);   // RNE
    return (unsigned short)(u >> 16);
}
__device__ __forceinline__ float bf2f(unsigned short h) {
    union { unsigned u; float f; } v; v.u = ((unsigned)h) << 16;
    return v.f;
}
__device__ __forceinline__ unsigned cvt_pk_bf16(float lo, float hi) {
    unsigned r;
    asm("v_cvt_pk_bf16_f32 %0, %1, %2" : "=v"(r) : "v"(lo), "v"(hi));
    return r;
}

__device__ __forceinline__ void gl16(const unsigned short* g, unsigned short* l) {
    __builtin_amdgcn_global_load_lds(
        (const __attribute__((address_space(1))) void*)g,
        (__attribute__((address_space(3))) void*)l, 16, 0, 0);
}

// ---------------- f32 -> bf16 conversion (grid-stride, G11) ----------------
// total = vec4 count; grid fixed at 1024 blocks (wo: 4194304 vec4 -> 16 iters/thread)
__global__ void __launch_bounds__(256) conv_f32_bf16(const float* __restrict__ in,
                                                     unsigned short* __restrict__ out,
                                                     unsigned total) {
    const unsigned nthr = gridDim.x * 256u;
    for (unsigned idx = blockIdx.x * 256u + threadIdx.x; idx < total; idx += nthr) {
        size_t i = (size_t)idx * 4;
        float4 v = *(const float4*)(in + i);
        ushort4 o;
        o.x = f2bf(v.x); o.y = f2bf(v.y); o.z = f2bf(v.z); o.w = f2bf(v.w);
        *(ushort4*)(out + i) = o;
    }
}

// Fused x|wq|wk|wv -> contiguous bf16 workspace (xb|wb|wkv). Grid-stride, 2048 blocks:
// 10485760 vec4 / 524288 threads = 20 iters/thread exactly.
__global__ void __launch_bounds__(256) conv_multi(const float* __restrict__ x,
                                                  const float* __restrict__ wq,
                                                  const float* __restrict__ wk,
                                                  const float* __restrict__ wv,
                                                  unsigned short* __restrict__ dst) {
    const unsigned nthr = gridDim.x * 256u;
    for (unsigned idx = blockIdx.x * 256u + threadIdx.x; idx < 10485760u; idx += nthr) {
        size_t i = (size_t)idx * 4;
        const float* s;
        if (i < 16777216u)      s = x  + i;
        else if (i < 33554432u) s = wq + (i - 16777216u);
        else if (i < 37748736u) s = wk + (i - 33554432u);
        else                    s = wv + (i - 37748736u);
        float4 v = *(const float4*)s;
        ushort4 o;
        o.x = f2bf(v.x); o.y = f2bf(v.y); o.z = f2bf(v.z); o.w = f2bf(v.w);
        *(ushort4*)(dst + i) = o;
    }
}

// ========== 256x256 8-phase NT GEMM (R9-R12/R15 proven schedule, 16x16x32 MFMA) ==========
// MODE: 0 = bf16 out, 1 = f32 out, 2 = bf16 out + fused RoPE(Q) * QS_LOG2E.
#define BAR() __builtin_amdgcn_s_barrier()
#define VMC4() asm volatile("s_waitcnt vmcnt(4)" ::: "memory")
#define VMC2() asm volatile("s_waitcnt vmcnt(2)" ::: "memory")

template<int MODE>
__global__ void __launch_bounds__(512, 2)
gemm256(const unsigned short* __restrict__ A, const unsigned short* __restrict__ Bm,
        void* __restrict__ Cv, int M, int N, int K,
        const float* __restrict__ fc, const float* __restrict__ fs) {
    __shared__ unsigned short ldsA[2][16384];
    __shared__ unsigned short ldsB[2][16384];

    const int tid = threadIdx.x;
    const int lane = tid & 63;
    const int w = tid >> 6;
    const int li = lane & 15, lg = lane >> 4;
    const int wr = w >> 2, wc = w & 3;

    const int nwg = gridDim.x;
    const int cpx = nwg >> 3;
    const int wg = (blockIdx.x & 7) * cpx + (blockIdx.x >> 3);
    const int nbn = N >> 8;
    const int bm = wg / nbn, bn = wg - bm * nbn;
    const int m0 = bm << 8, n0 = bn << 8;

    const int rbase = ((tid >> 7) << 4) + ((tid >> 2) & 15);
    const int cstg = ((tid >> 6) & 1) * 32 + (((tid & 3) * 8) ^ (((tid >> 5) & 1) << 4));
    const unsigned short* Abase = A + (size_t)(m0 + rbase) * K + cstg;
    const unsigned short* Bbase = Bm + (size_t)(n0 + rbase) * K + cstg;
    const int dstoff = tid * 8;
    const int kmask = K - 1;

    f32x4 acc[8][4];
#pragma unroll
    for (int i = 0; i < 8; ++i)
#pragma unroll
        for (int j = 0; j < 4; ++j) acc[i][j] = (f32x4){0.f, 0.f, 0.f, 0.f};

    const int colpart = (lg * 16) ^ ((li >> 3) << 5);

#define STG(BASE, LDSBUF, H, T) do {                                              \
        int kk_ = ((T) * 64) & kmask;                                             \
        gl16(BASE + (size_t)(((H) * 2 + 0) * 64) * K + kk_,                       \
             &LDSBUF[((H) * 2 + 0) * 4096 + dstoff]);                             \
        gl16(BASE + (size_t)(((H) * 2 + 1) * 64) * K + kk_,                       \
             &LDSBUF[((H) * 2 + 1) * 4096 + dstoff]);                             \
    } while (0)

#define LDBs(set, buf) do {                                                       \
        _Pragma("unroll")                                                         \
        for (int ni_ = 0; ni_ < 4; ++ni_) {                                       \
            _Pragma("unroll")                                                     \
            for (int ks_ = 0; ks_ < 2; ++ks_)                                     \
                bfr[set][ni_][ks_] = *(const bf16x8*)((const char*)&ldsB[buf][0]  \
                    + (wc * 4 + ni_) * 2048 + ks_ * 1024 + li * 64 + colpart);    \
        }                                                                         \
    } while (0)

#define LDAs(set, buf, q) do {                                                    \
        _Pragma("unroll")                                                         \
        for (int m_ = 0; m_ < 2; ++m_) {                                          \
            _Pragma("unroll")                                                     \
            for (int ks_ = 0; ks_ < 2; ++ks_)                                     \
                af[set][m_][ks_] = *(const bf16x8*)((const char*)&ldsA[buf][0]    \
                    + (wr * 8 + (q) * 2 + m_) * 2048 + ks_ * 1024 + li * 64 + colpart); \
        }                                                                         \
    } while (0)

#define MFMAs(sb, sa, q) do {                                                     \
        __builtin_amdgcn_s_setprio(1);                                            \
        _Pragma("unroll")                                                         \
        for (int ks_ = 0; ks_ < 2; ++ks_) {                                       \
            _Pragma("unroll")                                                     \
            for (int m_ = 0; m_ < 2; ++m_) {                                      \
                _Pragma("unroll")                                                 \
                for (int ni_ = 0; ni_ < 4; ++ni_)                                 \
                    acc[(q) * 2 + m_][ni_] = __builtin_amdgcn_mfma_f32_16x16x32_bf16( \
                        af[sa][m_][ks_], bfr[sb][ni_][ks_], acc[(q) * 2 + m_][ni_], 0, 0, 0); \
            }                                                                     \
        }                                                                         \
        __builtin_amdgcn_s_setprio(0);                                            \
    } while (0)

    STG(Abase, ldsA[0], 0, 0); STG(Abase, ldsA[0], 1, 0);
    STG(Bbase, ldsB[0], 0, 0); STG(Bbase, ldsB[0], 1, 0);
    STG(Bbase, ldsB[1], 0, 1); STG(Bbase, ldsB[1], 1, 1);
    VMC4();
    BAR();

    bf16x8 bfr[2][4][2], af[2][2][2];
    LDBs(0, 0);
    LDAs(0, 0, 0);

    const int NIT = K >> 7;
#pragma unroll 1
    for (int i = 0; i < NIT; ++i) {
        const int T = 2 * i;
        LDAs(1, 0, 1);
        STG(Abase, ldsA[1], 0, T + 1);
        MFMAs(0, 0, 0);
        BAR();
        LDAs(0, 0, 2);
        STG(Abase, ldsA[1], 1, T + 1);
        STG(Bbase, ldsB[0], 0, T + 2);
        MFMAs(0, 1, 1);
        BAR();
        LDAs(1, 0, 3);
        STG(Bbase, ldsB[0], 1, T + 2);
        MFMAs(0, 0, 2);
        VMC4();
        BAR();
        LDBs(1, 1);
        LDAs(0, 1, 0);
        MFMAs(0, 1, 3);
        BAR();
        LDAs(1, 1, 1);
        STG(Abase, ldsA[0], 0, T + 2);
        MFMAs(1, 0, 0);
        BAR();
        LDAs(0, 1, 2);
        STG(Abase, ldsA[0], 1, T + 2);
        STG(Bbase, ldsB[1], 0, T + 3);
        MFMAs(1, 1, 1);
        BAR();
        LDAs(1, 1, 3);
        STG(Bbase, ldsB[1], 1, T + 3);
        MFMAs(1, 0, 2);
        VMC4();
        BAR();
        LDBs(0, 0);
        LDAs(0, 0, 0);
        MFMAs(1, 1, 3);
        BAR();
    }

    const int r0 = m0 + wr * 128 + lg * 4;
    const int c0 = n0 + wc * 64 + li;
    if (MODE == 1) {
        float* C = (float*)Cv;
#pragma unroll
        for (int mi = 0; mi < 8; ++mi)
#pragma unroll
            for (int ni = 0; ni < 4; ++ni)
#pragma unroll
                for (int rr = 0; rr < 4; ++rr)
                    C[(size_t)(r0 + mi * 16 + rr) * N + c0 + ni * 16] = acc[mi][ni][rr];
    } else if (MODE == 0) {
        unsigned short* C = (unsigned short*)Cv;
#pragma unroll
        for (int mi = 0; mi < 8; ++mi)
#pragma unroll
            for (int ni = 0; ni < 4; ++ni)
#pragma unroll
                for (int rr = 0; rr < 4; ++rr)
                    C[(size_t)(r0 + mi * 16 + rr) * N + c0 + ni * 16] = f2bf(acc[mi][ni][rr]);
    } else {
        // fused RoPE(Q) + QS_LOG2E prescale
        unsigned short* C = (unsigned short*)Cv;
        const float sgn = (li & 1) ? 1.f : -1.f;
#pragma unroll
        for (int mi = 0; mi < 8; ++mi)
#pragma unroll
            for (int rr = 0; rr < 4; ++rr) {
                const int row = r0 + mi * 16 + rr;
                const int sidx = (row & (S_N - 1)) * 64;
#pragma unroll
                for (int ni = 0; ni < 4; ++ni) {
                    const int col = c0 + ni * 16;
                    const int ii = sidx + ((col & 127) >> 1);
                    float v = acc[mi][ni][rr];
                    float p = __shfl_xor(v, 1);
                    float o = (v * fc[ii] + sgn * p * fs[ii]) * QS_LOG2E;
                    C[(size_t)row * N + col] = f2bf(o);
                }
            }
    }
#undef STG
#undef LDBs
#undef LDAs
#undef MFMAs
}

// ========================= 256x128 8-phase NT GEMM (R10-R12/R15 proven) =========
template<int ROPEK>
__global__ void __launch_bounds__(512, 2)
gemm256x128(const unsigned short* __restrict__ A, const unsigned short* __restrict__ Bm,
            void* __restrict__ Cv, int M, int N, int K,
            const float* __restrict__ fc, const float* __restrict__ fs) {
    __shared__ unsigned short ldsA[2][16384];
    __shared__ unsigned short ldsB[2][8192];

    const int tid = threadIdx.x;
    const int lane = tid & 63;
    const int w = tid >> 6;
    const int li = lane & 15, lg = lane >> 4;
    const int wr = w >> 1, wc = w & 1;

    const int nwg = gridDim.x;
    const int cpx = nwg >> 3;
    const int wg = (blockIdx.x & 7) * cpx + (blockIdx.x >> 3);
    const int nbn = N >> 7;
    const int bm = wg / nbn, bn = wg - bm * nbn;
    const int m0 = bm << 8, n0 = bn << 7;

    const int rbase = ((tid >> 7) << 4) + ((tid >> 2) & 15);
    const int cstg = ((tid >> 6) & 1) * 32 + (((tid & 3) * 8) ^ (((tid >> 5) & 1) << 4));
    const unsigned short* Asrc[4];
    const unsigned short* Bsrc[2];
#pragma unroll
    for (int hj = 0; hj < 4; ++hj)
        Asrc[hj] = A + (size_t)(m0 + hj * 64 + rbase) * K + cstg;
#pragma unroll
    for (int hj = 0; hj < 2; ++hj)
        Bsrc[hj] = Bm + (size_t)(n0 + hj * 64 + rbase) * K + cstg;
    const int dstoff = tid * 8;
    const int kmask = K - 1;

    f32x4 acc[4][4];
#pragma unroll
    for (int i = 0; i < 4; ++i)
#pragma unroll
        for (int j = 0; j < 4; ++j) acc[i][j] = (f32x4){0.f, 0.f, 0.f, 0.f};

    const int colpart = (lg * 16) ^ ((li >> 3) << 5);

#define STG2(SRC, LDSBUF, H, T) do {                                        \
        int kk_ = ((T) * 64) & kmask;                                       \
        gl16(SRC[(H)*2 + 0] + kk_, &LDSBUF[((H)*2 + 0) * 4096 + dstoff]);   \
        gl16(SRC[(H)*2 + 1] + kk_, &LDSBUF[((H)*2 + 1) * 4096 + dstoff]);   \
    } while (0)

#define LDB2(buf) do {                                                       \
        _Pragma("unroll")                                                    \
        for (int ni_ = 0; ni_ < 4; ++ni_) {                                  \
            _Pragma("unroll")                                                \
            for (int ks_ = 0; ks_ < 2; ++ks_)                                \
                bfr[ni_][ks_] = *(const bf16x8*)((const char*)&ldsB[buf][0]  \
                    + (wc * 4 + ni_) * 2048 + ks_ * 1024 + li * 64 + colpart); \
        }                                                                    \
    } while (0)

#define LDA2(buf, q) do {                                                    \
        _Pragma("unroll")                                                    \
        for (int ks_ = 0; ks_ < 2; ++ks_)                                    \
            af2[ks_] = *(const bf16x8*)((const char*)&ldsA[buf][0]           \
                + (wr * 4 + (q)) * 2048 + ks_ * 1024 + li * 64 + colpart);   \
    } while (0)

#define MFMA8(q) do {                                                        \
        __builtin_amdgcn_s_setprio(1);                                       \
        _Pragma("unroll")                                                    \
        for (int ks_ = 0; ks_ < 2; ++ks_) {                                  \
            _Pragma("unroll")                                                \
            for (int ni_ = 0; ni_ < 4; ++ni_)                                \
                acc[q][ni_] = __builtin_amdgcn_mfma_f32_16x16x32_bf16(       \
                    af2[ks_], bfr[ni_][ks_], acc[q][ni_], 0, 0, 0);          \
        }                                                                    \
        __builtin_amdgcn_s_setprio(0);                                       \
    } while (0)

    STG2(Asrc, ldsA[0], 0, 0); STG2(Asrc, ldsA[0], 1, 0);
    STG2(Bsrc, ldsB[0], 0, 0);
    STG2(Bsrc, ldsB[1], 0, 1);
    VMC2();
    BAR();

    const int NIT = K >> 7;
    bf16x8 bfr[4][2], af2[2];
#pragma unroll 1
    for (int i = 0; i < NIT; ++i) {
        const int T = 2 * i;
        LDB2(0); LDA2(0, 0);
        STG2(Asrc, ldsA[1], 0, T + 1);
        BAR(); MFMA8(0); BAR();
        LDA2(0, 1);
        STG2(Asrc, ldsA[1], 1, T + 1);
        BAR(); MFMA8(1); BAR();
        LDA2(0, 2);
        STG2(Bsrc, ldsB[0], 0, T + 2);
        BAR(); MFMA8(2); BAR();
        LDA2(0, 3);
        VMC2();
        BAR(); MFMA8(3); BAR();
        LDB2(1); LDA2(1, 0);
        STG2(Asrc, ldsA[0], 0, T + 2);
        BAR(); MFMA8(0); BAR();
        LDA2(1, 1);
        STG2(Asrc, ldsA[0], 1, T + 2);
        BAR(); MFMA8(1); BAR();
        LDA2(1, 2);
        STG2(Bsrc, ldsB[1], 0, T + 3);
        BAR(); MFMA8(2); BAR();
        LDA2(1, 3);
        VMC2();
        BAR(); MFMA8(3); BAR();
    }

    const int r0 = m0 + wr * 64 + lg * 4;
    const int c0 = n0 + wc * 64 + li;
    unsigned short* C = (unsigned short*)Cv;
    if (ROPEK && bn < 8) {
        const float sgn = (li & 1) ? 1.f : -1.f;
#pragma unroll
        for (int mi = 0; mi < 4; ++mi)
#pragma unroll
            for (int rr = 0; rr < 4; ++rr) {
                const int row = r0 + mi * 16 + rr;
                const int sidx = (row & (S_N - 1)) * 64;
#pragma unroll
                for (int ni = 0; ni < 4; ++ni) {
                    const int col = c0 + ni * 16;
                    const int ii = sidx + ((col & 127) >> 1);
                    float v = acc[mi][ni][rr];
                    float p = __shfl_xor(v, 1);
                    float o = v * fc[ii] + sgn * p * fs[ii];
                    C[(size_t)row * N + col] = f2bf(o);
                }
            }
    } else {
#pragma unroll
        for (int mi = 0; mi < 4; ++mi)
#pragma unroll
            for (int ni = 0; ni < 4; ++ni)
#pragma unroll
                for (int rr = 0; rr < 4; ++rr)
                    C[(size_t)(r0 + mi * 16 + rr) * N + c0 + ni * 16] = f2bf(acc[mi][ni][rr]);
    }
#undef STG2
#undef LDB2
#undef LDA2
#undef MFMA8
}

// ======= Flash attention v9 (R12/R15, passed): GQA-fused 8-wave, register-P, defer-max =======
__device__ __forceinline__ void stage_k8(const unsigned short* kt_base,
                                         unsigned short* ks_base, int w, int lane) {
#pragma unroll
    for (int j = 0; j < 2; ++j) {
        int row = (w * 2 + j) * 4 + (lane >> 4);
        int colb = (lane & 15) * 16;
        int key = (row & 7) << 4;
        gl16(kt_base + (size_t)row * 2048 + ((colb ^ key) >> 1),
             ks_base + (w * 2 + j) * 512);
    }
}

__device__ __forceinline__ void load_v(const unsigned short* vt_base, int tid, uint4& a0, uint4& a1) {
    int kv = (tid >> 4) * 2, d0 = (tid & 15) * 8;
    const unsigned short* vp = vt_base + (size_t)kv * 2048 + d0;
    a0 = *(const uint4*)vp;
    a1 = *(const uint4*)(vp + 2048);
}

__device__ __forceinline__ void write_v(unsigned short* vt_lds, int tid, uint4 a0, uint4 a1) {
    int kv = (tid >> 4) * 2, d0 = (tid & 15) * 8;
    union { uint4 q; unsigned short u[8]; } x0, x1;
    x0.q = a0; x1.q = a1;
#pragma unroll
    for (int jj = 0; jj < 8; ++jj) {
        int d = d0 + jj;
        unsigned pack = (unsigned)x0.u[jj] | ((unsigned)x1.u[jj] << 16);
        int key = ((d ^ (d >> 3)) & 7) << 4;
        *(unsigned*)((char*)vt_lds + d * 128 + ((kv * 2) ^ key)) = pack;
    }
}

__global__ void __launch_bounds__(512, 2) attn_kernel(const unsigned short* __restrict__ Q,
                                                      const unsigned short* __restrict__ Kb,
                                                      const unsigned short* __restrict__ Vb,
                                                      unsigned short* __restrict__ O) {
    __shared__ unsigned short Ks[2][64 * 128];   // [kv][d], rows 256B
    __shared__ unsigned short Vt[2][128 * 64];   // [d][kv], rows 128B

    const int pidx = blockIdx.x;          // 0..15 pair index
    const int bg = blockIdx.y;            // b*8 + kvh
    const int b = bg >> 3, kvh = bg & 7;
    const int tid = threadIdx.x;
    const int w = tid >> 6, lane = tid & 63;
    const int li = lane & 15, lg = lane >> 4;
    const int h = kvh * 4 + (w >> 1);     // global head
    const int qh = (w & 1) * 32;          // q offset within 64-row tile

    const unsigned short* KVrow0 = Kb + (size_t)b * S_N * 2048 + kvh * 128;
    const unsigned short* Vrow0  = Vb + (size_t)b * S_N * 2048 + kvh * 128;

#pragma unroll 1
    for (int pass = 0; pass < 2; ++pass) {
        const int qt = pass ? (NQT - 1 - pidx) : pidx;
        const int nt = qt + 1;

        bf16x8 qf[2][4];
        {
            const unsigned short* qp = Q + ((size_t)b * S_N + qt * 64 + qh + li) * (H_N * HD_N)
                                         + h * HD_N + lg * 8;
#pragma unroll
            for (int mi = 0; mi < 2; ++mi)
#pragma unroll
                for (int ds = 0; ds < 4; ++ds)
                    qf[mi][ds] = *(const bf16x8*)(qp + (size_t)mi * 16 * (H_N * HD_N) + ds * 32);
        }

        float mreg[2], lreg[2];
#pragma unroll
        for (int mi = 0; mi < 2; ++mi) { mreg[mi] = -1e30f; lreg[mi] = 0.f; }
        f32x4 o_acc[2][8];
#pragma unroll
        for (int mi = 0; mi < 2; ++mi)
#pragma unroll
            for (int di = 0; di < 8; ++di) o_acc[mi][di] = (f32x4){0.f, 0.f, 0.f, 0.f};

        {
            stage_k8(KVrow0, &Ks[0][0], w, lane);
            uint4 a0, a1;
            load_v(Vrow0, tid, a0, a1);
            write_v(&Vt[0][0], tid, a0, a1);
        }
        __syncthreads();

#pragma unroll 1
        for (int t = 0; t < nt; ++t) {
            const int c = t & 1;
            const bool pre = (t + 1 < nt);
            uint4 a0, a1;
            if (pre) {
                stage_k8(KVrow0 + (size_t)(t + 1) * 64 * 2048, &Ks[c ^ 1][0], w, lane);
                load_v(Vrow0 + (size_t)(t + 1) * 64 * 2048, tid, a0, a1);
            }

            f32x4 sT[2][4];
#pragma unroll
            for (int mi = 0; mi < 2; ++mi)
#pragma unroll
                for (int ni = 0; ni < 4; ++ni) sT[mi][ni] = (f32x4){0.f, 0.f, 0.f, 0.f};
            __builtin_amdgcn_s_setprio(1);
#pragma unroll
            for (int ni = 0; ni < 4; ++ni) {
                const int kvc = ni * 16 + li;
                const int kkey = (kvc & 7) << 4;
                bf16x8 kf[4];
#pragma unroll
                for (int ds = 0; ds < 4; ++ds)
                    kf[ds] = *(const bf16x8*)((char*)&Ks[c][0] + kvc * 256
                                              + ((ds * 64 + lg * 16) ^ kkey));
#pragma unroll
                for (int mi = 0; mi < 2; ++mi)
#pragma unroll
                    for (int ds = 0; ds < 4; ++ds)
                        sT[mi][ni] = __builtin_amdgcn_mfma_f32_16x16x32_bf16(kf[ds], qf[mi][ds], sT[mi][ni], 0, 0, 0);
            }
            __builtin_amdgcn_s_setprio(0);

            if (t == qt) {
#pragma unroll
                for (int mi = 0; mi < 2; ++mi) {
                    int qq = qh + mi * 16 + li;
#pragma unroll
                    for (int ni = 0; ni < 4; ++ni)
#pragma unroll
                        for (int r = 0; r < 4; ++r)
                            if (ni * 16 + lg * 4 + r > qq) sT[mi][ni][r] = -1e30f;
                }
            }

            // ---- online softmax with defer-max ----
            float fac0[2];
            bool resc[2];
#pragma unroll
            for (int mi = 0; mi < 2; ++mi) {
                float pm = sT[mi][0][0];
#pragma unroll
                for (int ni = 0; ni < 4; ++ni)
#pragma unroll
                    for (int r = 0; r < 4; ++r) pm = fmaxf(pm, sT[mi][ni][r]);
                pm = fmaxf(pm, __shfl_xor(pm, 16));
                pm = fmaxf(pm, __shfl_xor(pm, 32));
                resc[mi] = !__all(pm <= mreg[mi] + 8.0f);
                fac0[mi] = 1.0f;
                if (resc[mi]) {
                    float mn = fmaxf(mreg[mi], pm);
                    fac0[mi] = __builtin_amdgcn_exp2f(mreg[mi] - mn);
                    mreg[mi] = mn;
                }
#pragma unroll
                for (int ni = 0; ni < 4; ++ni)
#pragma unroll
                    for (int r = 0; r < 4; ++r)
                        sT[mi][ni][r] = __builtin_amdgcn_exp2f(sT[mi][ni][r] - mreg[mi]);
                float rs = 0.f;
#pragma unroll
                for (int ni = 0; ni < 4; ++ni)
#pragma unroll
                    for (int r = 0; r < 4; ++r) rs += sT[mi][ni][r];
                rs += __shfl_xor(rs, 16);
                rs += __shfl_xor(rs, 32);
                lreg[mi] = lreg[mi] * fac0[mi] + rs;
            }

#pragma unroll
            for (int mi = 0; mi < 2; ++mi) {
                if (resc[mi]) {
                    float facR[4];
#pragma unroll
                    for (int rr = 0; rr < 4; ++rr)
                        facR[rr] = __shfl(fac0[mi], (lg << 4) | (lg * 4 + rr));
#pragma unroll
                    for (int di = 0; di < 8; ++di)
#pragma unroll
                        for (int rr = 0; rr < 4; ++rr) o_acc[mi][di][rr] *= facR[rr];
                }
            }

            union U { bf16x8 v; unsigned u[4]; };
            U pa[2][2];
#pragma unroll
            for (int mi = 0; mi < 2; ++mi)
#pragma unroll
                for (int ks = 0; ks < 2; ++ks) {
                    pa[mi][ks].u[0] = cvt_pk_bf16(sT[mi][2 * ks][0], sT[mi][2 * ks][1]);
                    pa[mi][ks].u[1] = cvt_pk_bf16(sT[mi][2 * ks][2], sT[mi][2 * ks][3]);
                    pa[mi][ks].u[2] = cvt_pk_bf16(sT[mi][2 * ks + 1][0], sT[mi][2 * ks + 1][1]);
                    pa[mi][ks].u[3] = cvt_pk_bf16(sT[mi][2 * ks + 1][2], sT[mi][2 * ks + 1][3]);
                }

            __builtin_amdgcn_s_setprio(1);
#pragma unroll
            for (int di = 0; di < 8; ++di) {
                int d = di * 16 + li;
                int vkey = ((d ^ (d >> 3)) & 7) << 4;
                const char* vbase = (const char*)&Vt[c][0] + d * 128;
                bf16x8 vf[2];
#pragma unroll
                for (int ks = 0; ks < 2; ++ks) {
                    union { bf16x8 v; unsigned long long g[2]; } vv;
                    int cb = ks * 64 + lg * 8;
                    vv.g[0] = *(const unsigned long long*)(vbase + (cb ^ vkey));
                    vv.g[1] = *(const unsigned long long*)(vbase + ((cb + 32) ^ vkey));
                    vf[ks] = vv.v;
                }
#pragma unroll
                for (int mi = 0; mi < 2; ++mi)
#pragma unroll
                    for (int ks = 0; ks < 2; ++ks)
                        o_acc[mi][di] = __builtin_amdgcn_mfma_f32_16x16x32_bf16(pa[mi][ks].v, vf[ks], o_acc[mi][di], 0, 0, 0);
            }
            __builtin_amdgcn_s_setprio(0);

            if (pre) write_v(&Vt[c ^ 1][0], tid, a0, a1);
            __syncthreads();
        }

        unsigned short* op = O + ((size_t)b * S_N + qt * 64 + qh + lg * 4) * (H_N * HD_N)
                               + h * HD_N + li;
#pragma unroll
        for (int mi = 0; mi < 2; ++mi) {
            float iv = 1.f / lreg[mi];
            float ivR[4];
#pragma unroll
            for (int rr = 0; rr < 4; ++rr)
                ivR[rr] = __shfl(iv, (lg << 4) | (lg * 4 + rr));
#pragma unroll
            for (int di = 0; di < 8; ++di)
#pragma unroll
                for (int rr = 0; rr < 4; ++rr)
                    op[((size_t)(mi * 16 + rr)) * (H_N * HD_N) + di * 16]
                        = f2bf(o_acc[mi][di][rr] * ivR[rr]);
        }
    }
}

// ---------------- launch ----------------
extern "C" void kernel_launch(void* const* d_in, const int* in_sizes, int n_in,
                              void* d_out, int out_size, void* d_ws, size_t ws_size,
                              hipStream_t stream) {
    (void)in_sizes; (void)n_in; (void)out_size; (void)ws_size;
    const float* x  = (const float*)d_in[0];
    const float* wq = (const float*)d_in[1];
    const float* wk = (const float*)d_in[2];
    const float* wv = (const float*)d_in[3];
    const float* wo = (const float*)d_in[4];
    const float* fc = (const float*)d_in[5];
    const float* fs = (const float*)d_in[6];
    float* out = (float*)d_out;

    char* ws = (char*)d_ws;
    unsigned short* xb  = (unsigned short*)(ws);                // 33.5MB  x bf16
    unsigned short* wb  = (unsigned short*)(ws + 33554432);     // 33.5MB  wq, later wo
    unsigned short* wkv = (unsigned short*)(ws + 67108864);     // 16.8MB  [wk;wv]
    unsigned short* Qb  = (unsigned short*)(ws + 83886080);     // 33.5MB  Q, later attn-O
    unsigned short* KVb = (unsigned short*)(ws + 117440512);    // 16.8MB  [K|V] rows of 2048

    const int BS = B_N * S_N;  // 4096

    // fused f32->bf16: x|wq|wk|wv -> xb|wb|wkv (grid-stride, 2048 blocks, 20 vec4/thread)
    conv_multi<<<dim3(2048), 256, 0, stream>>>(x, wq, wk, wv, xb);

    // Q = rope(x wq^T) * QS_LOG2E  (bf16 out, fused RoPE epilogue)
    gemm256<2><<<dim3((BS / 256) * (D_N / 256)), 512, 0, stream>>>(xb, wb, Qb, BS, D_N, D_N, fc, fs);
    // wo -> wb (grid-stride, 1024 blocks, 16 vec4/thread)
    conv_f32_bf16<<<dim3(1024), 256, 0, stream>>>(wo, wb, (unsigned)(D_N * H_N * HD_N / 4));
    // [K|V] = x [wk;wv]^T, 256x128 tile (grid 256), RoPE fused on K columns
    gemm256x128<1><<<dim3((BS / 256) * (2048 / 128)), 512, 0, stream>>>(xb, wkv, KVb, BS, 2048, D_N, fc, fs);

    // attention: GQA-fused 256 blocks (1/CU), 8 waves, register-P, defer-max
    attn_kernel<<<dim3(NQT / 2, B_N * KVH_N), 512, 0, stream>>>(Qb, KVb, KVb + 1024, Qb);

    // out = O wo^T (f32 out)
    gemm256<1><<<dim3((BS / 256) * (D_N / 256)), 512, 0, stream>>>(Qb, wb, out, BS, D_N, D_N, fc, fs);
}